// Round 1
// baseline (134.802 us; speedup 1.0000x reference)
//
#include <hip/hip_runtime.h>
#include <cstdint>

constexpr int N_NODES  = 2048;
constexpr int N_EDGES  = 16384;
constexpr int NS       = 16;                 // node-axis split
constexpr int CHUNK    = N_NODES / NS;       // 128 nodes per chunk
constexpr int EPT      = 4;                  // edges per thread (float4 loads)
constexpr int K1_BLOCK = 256;
constexpr int GROUPS   = N_EDGES / EPT;      // 4096 edge-groups

// ---------------------------------------------------------------------------
// K1: partial GEMMs.  part layout: [NS][8][N_EDGES] floats (8 MB in d_ws).
// slot 0..3 = bo (Ro-based), slot 4..7 = bi (Ri-based)  -- matches
// angles = concat([bo, bi], axis=1) in the reference.
// ---------------------------------------------------------------------------
__global__ __launch_bounds__(K1_BLOCK) void k1_partial(
    const float* __restrict__ X,
    const float* __restrict__ Ri,
    const float* __restrict__ Ro,
    float* __restrict__ part)
{
    __shared__ float4 xs[CHUNK];
    const int ns  = blockIdx.y;
    const int n0  = ns * CHUNK;
    const int tid = threadIdx.x;
    if (tid < CHUNK) xs[tid] = reinterpret_cast<const float4*>(X)[n0 + tid];
    __syncthreads();

    const int g = blockIdx.x * K1_BLOCK + tid;           // [0, GROUPS)
    const float4* Ro4 = reinterpret_cast<const float4*>(Ro);
    const float4* Ri4 = reinterpret_cast<const float4*>(Ri);

    float acc_o[EPT][4];
    float acc_i[EPT][4];
    #pragma unroll
    for (int el = 0; el < EPT; ++el)
        #pragma unroll
        for (int q = 0; q < 4; ++q) { acc_o[el][q] = 0.f; acc_i[el][q] = 0.f; }

    #pragma unroll 4
    for (int k = 0; k < CHUNK; ++k) {
        const int n = n0 + k;
        const float4 ro = Ro4[n * (N_EDGES / 4) + g];
        const float4 ri = Ri4[n * (N_EDGES / 4) + g];
        const float4 x  = xs[k];
        const float roa[EPT] = {ro.x, ro.y, ro.z, ro.w};
        const float ria[EPT] = {ri.x, ri.y, ri.z, ri.w};
        const float xa[4]    = {x.x,  x.y,  x.z,  x.w};
        #pragma unroll
        for (int el = 0; el < EPT; ++el)
            #pragma unroll
            for (int q = 0; q < 4; ++q) {
                acc_o[el][q] = fmaf(roa[el], xa[q], acc_o[el][q]);
                acc_i[el][q] = fmaf(ria[el], xa[q], acc_i[el][q]);
            }
    }

    // coalesced float4 stores: edge e = 4*g + el  ->  component el of float4[g]
    #pragma unroll
    for (int q = 0; q < 4; ++q) {
        const float4 vo = make_float4(acc_o[0][q], acc_o[1][q], acc_o[2][q], acc_o[3][q]);
        const float4 vi = make_float4(acc_i[0][q], acc_i[1][q], acc_i[2][q], acc_i[3][q]);
        reinterpret_cast<float4*>(part + (size_t)(ns * 8 + q)     * N_EDGES)[g] = vo;
        reinterpret_cast<float4*>(part + (size_t)(ns * 8 + 4 + q) * N_EDGES)[g] = vi;
    }
}

// ---------------------------------------------------------------------------
// K2: 8-qubit real-amplitude circuit per edge, state in registers.
// Flat index bit for qubit q is (7-q)  (axis 1 = qubit 0 = MSB).
// ---------------------------------------------------------------------------
template<int Q>
__device__ __forceinline__ void build_level(float* st, float c, float s) {
    constexpr int SZ = 1 << Q;
    #pragma unroll
    for (int i = SZ - 1; i >= 0; --i) {          // downward: in-place safe
        const float v = st[i];
        st[2 * i]     = v * c;
        st[2 * i + 1] = v * s;
    }
}

template<int W>
__device__ __forceinline__ void ry_op(float* st, float c, float s) {
    constexpr int STRIDE = 1 << (7 - W);
    #pragma unroll
    for (int base = 0; base < 256; base += 2 * STRIDE)
        #pragma unroll
        for (int j = 0; j < STRIDE; ++j) {
            const int i0 = base + j, i1 = i0 + STRIDE;
            const float a0 = st[i0], a1 = st[i1];
            st[i0] = fmaf(c, a0, -(s * a1));
            st[i1] = fmaf(s, a0,   c * a1);
        }
}

template<int C, int T>
__device__ __forceinline__ void cx_op(float* st) {
    constexpr int CB = 1 << (7 - C);
    constexpr int TB = 1 << (7 - T);
    #pragma unroll
    for (int i = 0; i < 256; ++i) {
        if ((i & CB) && !(i & TB)) {
            const float t = st[i];
            st[i]        = st[i | TB];
            st[i | TB]   = t;
        }
    }
}

__global__ __launch_bounds__(64, 1) void k2_circuit(
    const float* __restrict__ part,
    const float* __restrict__ theta,
    float* __restrict__ out)
{
    const int e = blockIdx.x * 64 + threadIdx.x;

    // reduce the NS partial sums -> 8 angles (coalesced dword loads)
    float a[8];
    #pragma unroll
    for (int q = 0; q < 8; ++q) a[q] = 0.f;
    #pragma unroll
    for (int ns = 0; ns < NS; ++ns)
        #pragma unroll
        for (int slot = 0; slot < 8; ++slot)
            a[slot] += part[(size_t)(ns * 8 + slot) * N_EDGES + e];

    // initial product state
    float st[256];
    {
        float c0, s0;
        sincosf(0.5f * a[0], &s0, &c0);          // large args: full range reduction
        st[0] = c0; st[1] = s0;
    }
    { float c, s; sincosf(0.5f * a[1], &s, &c); build_level<1>(st, c, s); }
    { float c, s; sincosf(0.5f * a[2], &s, &c); build_level<2>(st, c, s); }
    { float c, s; sincosf(0.5f * a[3], &s, &c); build_level<3>(st, c, s); }
    { float c, s; sincosf(0.5f * a[4], &s, &c); build_level<4>(st, c, s); }
    { float c, s; sincosf(0.5f * a[5], &s, &c); build_level<5>(st, c, s); }
    { float c, s; sincosf(0.5f * a[6], &s, &c); build_level<6>(st, c, s); }
    { float c, s; sincosf(0.5f * a[7], &s, &c); build_level<7>(st, c, s); }

    // circuit: theta/2 in [0, 2pi] -> fast sincos is accurate enough
#define RY(W, IDX) { float c_, s_; __sincosf(0.5f * theta[IDX], &s_, &c_); ry_op<W>(st, c_, s_); }
    RY(1, 0)  RY(2, 1)  cx_op<1, 2>(st);
    RY(5, 2)  RY(6, 3)  cx_op<6, 5>(st);
    RY(0, 4)  RY(1, 5)  cx_op<0, 1>(st);
    RY(2, 6)  RY(3, 7)  cx_op<3, 2>(st);
    RY(4, 8)  RY(5, 9)  cx_op<4, 5>(st);
    RY(6, 10) RY(7, 11) cx_op<7, 6>(st);
    RY(2, 12) RY(5, 13) cx_op<2, 5>(st);
    RY(1, 14) RY(2, 15) cx_op<1, 2>(st);
    RY(5, 16) RY(6, 17) cx_op<6, 5>(st);
    RY(2, 18) RY(5, 19) cx_op<2, 5>(st);
    RY(5, 20)
#undef RY

    // measure qubit 5 (bit 2 of flat index)
    float sum0[4] = {0.f, 0.f, 0.f, 0.f};
    float sum1[4] = {0.f, 0.f, 0.f, 0.f};
    #pragma unroll
    for (int i = 0; i < 256; ++i) {
        if (i & 4) sum1[i & 3] = fmaf(st[i], st[i], sum1[i & 3]);
        else       sum0[i & 3] = fmaf(st[i], st[i], sum0[i & 3]);
    }
    const float m1 = (sum1[0] + sum1[1]) + (sum1[2] + sum1[3]);
    const float m0 = (sum0[0] + sum0[1]) + (sum0[2] + sum0[3]);
    out[e] = 0.5f * (1.0f - m0 + m1);
}

// ---------------------------------------------------------------------------
extern "C" void kernel_launch(void* const* d_in, const int* in_sizes, int n_in,
                              void* d_out, int out_size, void* d_ws, size_t ws_size,
                              hipStream_t stream)
{
    const float* X     = (const float*)d_in[0];
    const float* Ri    = (const float*)d_in[1];
    const float* Ro    = (const float*)d_in[2];
    const float* theta = (const float*)d_in[3];
    float* part = (float*)d_ws;                  // NS*8*N_EDGES floats = 8 MB
    float* outp = (float*)d_out;

    dim3 g1(GROUPS / K1_BLOCK, NS);              // (16, 16)
    k1_partial<<<g1, dim3(K1_BLOCK), 0, stream>>>(X, Ri, Ro, part);
    k2_circuit<<<dim3(N_EDGES / 64), dim3(64), 0, stream>>>(part, theta, outp);
}

// Round 2
// 60.977 us; speedup vs baseline: 2.2107x; 2.2107x over previous
//
#include <hip/hip_runtime.h>
#include <cstdint>

constexpr int N_NODES  = 2048;
constexpr int N_EDGES  = 16384;
constexpr int NS       = 16;                 // node-axis split (part slices)
constexpr int CHUNK    = N_NODES / NS;       // 128 nodes per slice
constexpr int KSUB     = 4;                  // intra-block k-split
constexpr int SUBCHUNK = CHUNK / KSUB;       // 32 nodes per thread
constexpr int TG       = 64;                 // edge-groups (float4) per block
constexpr int EPT      = 4;                  // edges per group
constexpr int K1_BLOCK = TG * KSUB;          // 256
constexpr int GROUPS   = N_EDGES / EPT;      // 4096

// ---------------------------------------------------------------------------
// K1: partial GEMMs.  part layout: [NS][N_EDGES][8] floats (8 MB in d_ws).
// per-edge 8 floats = (bo[0..3], bi[0..3])  (angles = concat([bo,bi],axis=1))
// ---------------------------------------------------------------------------
__global__ __launch_bounds__(K1_BLOCK) void k1_partial(
    const float* __restrict__ X,
    const float* __restrict__ Ri,
    const float* __restrict__ Ro,
    float* __restrict__ part)
{
    __shared__ float4 xs[CHUNK];
    __shared__ float  red[KSUB][TG][33];     // +1 pad -> conflict-free

    const int ns  = blockIdx.y;
    const int n0  = ns * CHUNK;
    const int tid = threadIdx.x;
    const int gl  = tid & (TG - 1);          // edge-group lane within block
    const int ks  = tid >> 6;                // k-sub-chunk index

    if (tid < CHUNK) xs[tid] = reinterpret_cast<const float4*>(X)[n0 + tid];
    __syncthreads();

    const int g = blockIdx.x * TG + gl;      // [0, GROUPS)
    const float4* Ro4 = reinterpret_cast<const float4*>(Ro);
    const float4* Ri4 = reinterpret_cast<const float4*>(Ri);

    float acc_o[EPT][4];
    float acc_i[EPT][4];
    #pragma unroll
    for (int el = 0; el < EPT; ++el)
        #pragma unroll
        for (int q = 0; q < 4; ++q) { acc_o[el][q] = 0.f; acc_i[el][q] = 0.f; }

    const int kbase = n0 + ks * SUBCHUNK;
    #pragma unroll 8
    for (int k = 0; k < SUBCHUNK; ++k) {
        const int n = kbase + k;
        const float4 ro = Ro4[n * (N_EDGES / 4) + g];
        const float4 ri = Ri4[n * (N_EDGES / 4) + g];
        const float4 x  = xs[n - n0];
        const float roa[EPT] = {ro.x, ro.y, ro.z, ro.w};
        const float ria[EPT] = {ri.x, ri.y, ri.z, ri.w};
        const float xa[4]    = {x.x,  x.y,  x.z,  x.w};
        #pragma unroll
        for (int el = 0; el < EPT; ++el)
            #pragma unroll
            for (int q = 0; q < 4; ++q) {
                acc_o[el][q] = fmaf(roa[el], xa[q], acc_o[el][q]);
                acc_i[el][q] = fmaf(ria[el], xa[q], acc_i[el][q]);
            }
    }

    // stash 32 partials: v = q*4+el (bo), 16 + q*4+el (bi)
    #pragma unroll
    for (int q = 0; q < 4; ++q)
        #pragma unroll
        for (int el = 0; el < EPT; ++el) {
            red[ks][gl][q * 4 + el]      = acc_o[el][q];
            red[ks][gl][16 + q * 4 + el] = acc_i[el][q];
        }
    __syncthreads();

    if (ks == 0) {
        float sum[32];
        #pragma unroll
        for (int v = 0; v < 32; ++v)
            sum[v] = ((red[0][gl][v] + red[1][gl][v]) +
                      (red[2][gl][v] + red[3][gl][v]));
        #pragma unroll
        for (int el = 0; el < EPT; ++el) {
            const int e = 4 * g + el;
            float4* dst = reinterpret_cast<float4*>(part + ((size_t)ns * N_EDGES + e) * 8);
            dst[0] = make_float4(sum[0 * 4 + el], sum[1 * 4 + el], sum[2 * 4 + el], sum[3 * 4 + el]);
            dst[1] = make_float4(sum[16 + 0 * 4 + el], sum[16 + 1 * 4 + el],
                                 sum[16 + 2 * 4 + el], sum[16 + 3 * 4 + el]);
        }
    }
}

// ---------------------------------------------------------------------------
// K2: 8-qubit circuit, state split across 4 lanes (64 amplitudes per lane).
// Flat amp index i[7:0]: qubit q <-> bit (7-q).
//   i[7:6] = lane sub-index (qubit0 = sub bit1, qubit1 = sub bit0)
//   i[5:0] = register index j (qubit2 = j bit5 ... qubit7 = j bit0)
// ---------------------------------------------------------------------------
template<int LVL>
__device__ __forceinline__ void build64(float* st, float c, float s) {
    #pragma unroll
    for (int i = (1 << LVL) - 1; i >= 0; --i) {  // downward: in-place safe
        const float v = st[i];
        st[2 * i]     = v * c;
        st[2 * i + 1] = v * s;
    }
}

template<int W>   // W in [2..7], lane-local RY
__device__ __forceinline__ void ry64(float* st, float c, float s) {
    constexpr int STRIDE = 1 << (7 - W);
    #pragma unroll
    for (int base = 0; base < 64; base += 2 * STRIDE)
        #pragma unroll
        for (int j = 0; j < STRIDE; ++j) {
            const int i0 = base + j, i1 = i0 + STRIDE;
            const float a0 = st[i0], a1 = st[i1];
            st[i0] = fmaf(c, a0, -(s * a1));
            st[i1] = fmaf(s, a0,   c * a1);
        }
}

// RY on qubit 0 or 1 (lane bits). mask: 2 for q0, 1 for q1. mybit: this lane's bit.
__device__ __forceinline__ void ry_cross(float* st, float c, float s, int mask, int mybit) {
    const float ss = mybit ? s : -s;
    #pragma unroll
    for (int j = 0; j < 64; ++j) {
        const float other = __shfl_xor(st[j], mask, 64);
        st[j] = fmaf(c, st[j], ss * other);
    }
}

template<int CB, int TB>   // both bits inside the 64-reg index: free permutation
__device__ __forceinline__ void cx_reg(float* st) {
    #pragma unroll
    for (int i = 0; i < 64; ++i)
        if ((i & CB) && !(i & TB)) {
            const float t = st[i]; st[i] = st[i | TB]; st[i | TB] = t;
        }
}

__global__ __launch_bounds__(256, 2) void k2_circuit(
    const float* __restrict__ part,
    const float* __restrict__ theta,
    float* __restrict__ out)
{
    const int tid = threadIdx.x;
    const int sub = tid & 3;                      // i[7:6]
    const int e   = blockIdx.x * 64 + (tid >> 2); // edge
    const int p0  = (sub >> 1) & 1;               // qubit-0 bit
    const int p1  = sub & 1;                      // qubit-1 bit

    // ---- angles: each lane loads 4 of the 16 slices, then quad-reduce ----
    float a[8] = {0.f, 0.f, 0.f, 0.f, 0.f, 0.f, 0.f, 0.f};
    #pragma unroll
    for (int r = 0; r < 4; ++r) {
        const int ns = sub * 4 + r;
        const float4* p4 = reinterpret_cast<const float4*>(
            part + ((size_t)ns * N_EDGES + e) * 8);
        const float4 lo = p4[0], hi = p4[1];
        a[0] += lo.x; a[1] += lo.y; a[2] += lo.z; a[3] += lo.w;
        a[4] += hi.x; a[5] += hi.y; a[6] += hi.z; a[7] += hi.w;
    }
    #pragma unroll
    for (int q = 0; q < 8; ++q) {
        a[q] += __shfl_xor(a[q], 1, 64);
        a[q] += __shfl_xor(a[q], 2, 64);
    }

    // ---- initial product state (full range reduction: angles are large) ----
    float st[64];
    {
        float c, s, f;
        sincosf(0.5f * a[0], &s, &c); f  = p0 ? s : c;
        sincosf(0.5f * a[1], &s, &c); f *= p1 ? s : c;
        st[0] = f;
        sincosf(0.5f * a[2], &s, &c); build64<0>(st, c, s);
        sincosf(0.5f * a[3], &s, &c); build64<1>(st, c, s);
        sincosf(0.5f * a[4], &s, &c); build64<2>(st, c, s);
        sincosf(0.5f * a[5], &s, &c); build64<3>(st, c, s);
        sincosf(0.5f * a[6], &s, &c); build64<4>(st, c, s);
        sincosf(0.5f * a[7], &s, &c); build64<5>(st, c, s);
    }

    // ---- circuit (theta/2 bounded -> fast sincos) ----
#define THC(IDX) float c_, s_; __sincosf(0.5f * theta[IDX], &s_, &c_)
#define RYL(W, IDX) { THC(IDX); ry64<W>(st, c_, s_); }
#define RY0(IDX)    { THC(IDX); ry_cross(st, c_, s_, 2, p0); }
#define RY1(IDX)    { THC(IDX); ry_cross(st, c_, s_, 1, p1); }

    RY1(0) RYL(2, 1)
    {   // cx(1,2): control = lane bit p1, target = reg bit5
        #pragma unroll
        for (int j = 0; j < 32; ++j) {
            const float t0 = st[j], t1 = st[j + 32];
            st[j]      = p1 ? t1 : t0;
            st[j + 32] = p1 ? t0 : t1;
        }
    }
    RYL(5, 2) RYL(6, 3) cx_reg<2, 4>(st);           // cx(6,5)
    RY0(4) RY1(5)
    {   // cx(0,1): control = p0, target = lane bit p1 -> sub 2<->3 swap
        #pragma unroll
        for (int j = 0; j < 64; ++j) {
            const float other = __shfl_xor(st[j], 1, 64);
            st[j] = p0 ? other : st[j];
        }
    }
    RYL(2, 6) RYL(3, 7) cx_reg<16, 32>(st);         // cx(3,2)
    RYL(4, 8) RYL(5, 9) cx_reg<8, 4>(st);           // cx(4,5)
    RYL(6, 10) RYL(7, 11) cx_reg<1, 2>(st);         // cx(7,6)
    RYL(2, 12) RYL(5, 13) cx_reg<32, 4>(st);        // cx(2,5)
    RY1(14) RYL(2, 15)
    {   // cx(1,2) again
        #pragma unroll
        for (int j = 0; j < 32; ++j) {
            const float t0 = st[j], t1 = st[j + 32];
            st[j]      = p1 ? t1 : t0;
            st[j + 32] = p1 ? t0 : t1;
        }
    }
    RYL(5, 16) RYL(6, 17) cx_reg<2, 4>(st);         // cx(6,5)
    RYL(2, 18) RYL(5, 19) cx_reg<32, 4>(st);        // cx(2,5)
    RYL(5, 20)
#undef RYL
#undef RY0
#undef RY1
#undef THC

    // ---- measure qubit 5 (reg bit 2): d = m1 - m0, reduce over quad ----
    float m0 = 0.f, m1 = 0.f;
    #pragma unroll
    for (int j = 0; j < 64; ++j) {
        if (j & 4) m1 = fmaf(st[j], st[j], m1);
        else       m0 = fmaf(st[j], st[j], m0);
    }
    float d = m1 - m0;
    d += __shfl_xor(d, 1, 64);
    d += __shfl_xor(d, 2, 64);
    if (sub == 0) out[e] = 0.5f * (1.0f + d);
}

// ---------------------------------------------------------------------------
extern "C" void kernel_launch(void* const* d_in, const int* in_sizes, int n_in,
                              void* d_out, int out_size, void* d_ws, size_t ws_size,
                              hipStream_t stream)
{
    const float* X     = (const float*)d_in[0];
    const float* Ri    = (const float*)d_in[1];
    const float* Ro    = (const float*)d_in[2];
    const float* theta = (const float*)d_in[3];
    float* part = (float*)d_ws;                  // NS*N_EDGES*8 floats = 8 MB
    float* outp = (float*)d_out;

    dim3 g1(GROUPS / TG, NS);                    // (64, 16)
    k1_partial<<<g1, dim3(K1_BLOCK), 0, stream>>>(X, Ri, Ro, part);
    k2_circuit<<<dim3(N_EDGES / 64), dim3(256), 0, stream>>>(part, theta, outp);
}